// Round 6
// baseline (33736.655 us; speedup 1.0000x reference)
//
#include <hip/hip_runtime.h>
#include <cstddef>
#include <cstdint>

// Problem: GRU  B=32, L=1024, D_IN=512, H=512
// outputs: outs(32,1024,512) then h_last(32,512), flat in d_out.

#define Bsz   32
#define Lsz   1024
#define Hsz   512
#define NG    1536   // 1024 ru gates + 512 cand

// recurrence decomposition
#define NBLK    256   // blocks (co-resident, cooperative launch)
#define GROUPS  4     // batch groups (8 batches each)
#define SLICES  64    // weight slices per group (one block each)
#define BPAIRS  4     // batch-pairs per group = waves per block (independent sync domains)
#define NDOM    (GROUPS * BPAIRS)   // 16 sync domains
#define JB      8     // h-columns owned per slice
#define LDW     512   // LDS row stride in floats (16B aligned, contiguous b128 reads)
#define THREADS 256
#define FSTR    16    // counter stride in u32 (64B: one cache line per counter)

typedef float f32x4 __attribute__((ext_vector_type(4)));

__device__ __forceinline__ float sigmoidf_(float v) {
    return 1.0f / (1.0f + __expf(-v));
}
__device__ __forceinline__ float tanhf_(float v) {
    float e = __expf(2.0f * v);           // inf -> 1, 0 -> -1 : correct saturation
    return 1.0f - 2.0f / (e + 1.0f);
}
// agent-scope (device) accesses; L3 is the coherence point.  ALL cross-wave
// data uses agent scope on BOTH sides (R5 lesson: system-scope sc0 sc1 loads
// against agent-scope stores opened a stale-read window).
__device__ __forceinline__ float ld_agent(const float* p) {
    return __hip_atomic_load(p, __ATOMIC_RELAXED, __HIP_MEMORY_SCOPE_AGENT);
}
__device__ __forceinline__ void st_agent(float* p, float v) {
    __hip_atomic_store(p, v, __ATOMIC_RELAXED, __HIP_MEMORY_SCOPE_AGENT);
}
// four agent-scope (sc1) 16B loads, one waitcnt.  The internal vmcnt(0) also
// guarantees these loads COMPLETE before any later arrive-add in this wave
// (the WAR handshake relies on this).
__device__ __forceinline__ void ld4_agent(const float* p, f32x4& a, f32x4& b,
                                          f32x4& c, f32x4& d) {
    asm volatile(
        "global_load_dwordx4 %0, %4, off sc1\n\t"
        "global_load_dwordx4 %1, %4, off offset:1024 sc1\n\t"
        "global_load_dwordx4 %2, %4, off offset:2048 sc1\n\t"
        "global_load_dwordx4 %3, %4, off offset:3072 sc1\n\t"
        "s_waitcnt vmcnt(0)"
        : "=&v"(a), "=&v"(b), "=&v"(c), "=&v"(d)
        : "v"(p)
        : "memory");
}

// ---- counting barrier primitives (single line per domain-phase) ----------
// arrive: fire-and-forget RMW; RELEASE drains this wave's prior data stores
// (adds from the 64 slices pipeline into one L3 bank -- no round-trips).
__device__ __forceinline__ void arrive(unsigned* c) {
    __hip_atomic_fetch_add(c, 1u, __ATOMIC_RELEASE, __HIP_MEMORY_SCOPE_AGENT);
}
// wait: all 64 lanes poll ONE address (one coalesced request per iteration)
// with sleep backoff -> ~60x less L3 poll pressure than R4's 64-line gather.
// Running-sum threshold 64*s bounds inter-slice skew to exactly 1 step
// (if any slice exceeded min+1, total >= 64(m+1) while sum <= 64m+63).
__device__ __forceinline__ void wait_cnt(const unsigned* c, unsigned target) {
    while (__hip_atomic_load(c, __ATOMIC_RELAXED, __HIP_MEMORY_SCOPE_AGENT) < target)
        __builtin_amdgcn_s_sleep(2);
}

// fold an 8-array over lane-xor {1,2,4}: returns this lane's partial sum of
// element (l&7) over its 8-lane subgroup.  Partition-agnostic over k.
__device__ __forceinline__ float fold8(float a[8], int l) {
    #pragma unroll
    for (int i = 0; i < 4; ++i) {
        float lo = a[2 * i], hi = a[2 * i + 1];
        float ex = __shfl_xor((l & 1) ? lo : hi, 1);
        a[i] = (l & 1) ? (hi + ex) : (lo + ex);
    }
    #pragma unroll
    for (int i = 0; i < 2; ++i) {
        float lo = a[2 * i], hi = a[2 * i + 1];
        float ex = __shfl_xor((l & 2) ? lo : hi, 2);
        a[i] = (l & 2) ? (hi + ex) : (lo + ex);
    }
    float lo = a[0], hi = a[1];
    float ex = __shfl_xor((l & 4) ? lo : hi, 4);
    return (l & 4) ? (hi + ex) : (lo + ex);
}
// combine batch0/batch1 partials over xor8 (lane keeps batch (l>>3)&1),
// then full-add over xor16/xor32.  Result: lane l holds the COMPLETE k-sum
// for (batch=(l>>3)&1, column=l&7); lanes 0..15 are the owners.
__device__ __forceinline__ float fold_b(float p0, float p1, int l) {
    float send = (l & 8) ? p0 : p1;
    float ex   = __shfl_xor(send, 8);
    float keep = (l & 8) ? p1 : p0;
    float v = keep + ex;
    v += __shfl_xor(v, 16);
    v += __shfl_xor(v, 32);
    return v;
}

__global__ __launch_bounds__(256) void init_h(const float* __restrict__ h0,
                                              float* __restrict__ hstate) {
    int i = blockIdx.x * 256 + threadIdx.x;
    hstate[i] = h0[i];   // parity-0 buffer
}

// ---------------- input-projection GEMM (unchanged) ------------------------
__global__ __launch_bounds__(256) void gemm_pre(const float* __restrict__ x,
                                                const float* __restrict__ W_ru,
                                                const float* __restrict__ b_ru,
                                                const float* __restrict__ W_c,
                                                const float* __restrict__ b_c,
                                                float* __restrict__ pre,
                                                int t0) {
    __shared__ float As[8][128];
    __shared__ float Bs[8][128];
    const int tid = threadIdx.x;
    const int bm = blockIdx.x, bn = blockIdx.y;
    const int tx = tid & 15, ty = tid >> 4;

    const int lrow = tid >> 1;
    const int lk4  = (tid & 1) * 4;
    const int grow = bm * 128 + lrow;          // row = t_local*32 + b
    const int tt = grow >> 5, bb = grow & 31;
    const float* xrow = x + ((size_t)bb * Lsz + (t0 + tt)) * 512;
    const int gn = bn * 128 + lrow;            // output column (gate index)
    const float* wrow = (gn < 1024) ? (W_ru + (size_t)gn * 1024 + 512)
                                    : (W_c  + (size_t)(gn - 1024) * 1024 + 512);

    float acc[8][8];
    #pragma unroll
    for (int i = 0; i < 8; ++i)
        #pragma unroll
        for (int j = 0; j < 8; ++j) acc[i][j] = 0.0f;

    for (int k0 = 0; k0 < 512; k0 += 8) {
        float4 av = *(const float4*)(xrow + k0 + lk4);
        float4 bv = *(const float4*)(wrow + k0 + lk4);
        __syncthreads();
        As[lk4 + 0][lrow] = av.x; As[lk4 + 1][lrow] = av.y;
        As[lk4 + 2][lrow] = av.z; As[lk4 + 3][lrow] = av.w;
        Bs[lk4 + 0][lrow] = bv.x; Bs[lk4 + 1][lrow] = bv.y;
        Bs[lk4 + 2][lrow] = bv.z; Bs[lk4 + 3][lrow] = bv.w;
        __syncthreads();
        #pragma unroll
        for (int k = 0; k < 8; ++k) {
            float a[8], b[8];
            *(float4*)&a[0] = *(const float4*)&As[k][ty * 8];
            *(float4*)&a[4] = *(const float4*)&As[k][ty * 8 + 4];
            *(float4*)&b[0] = *(const float4*)&Bs[k][tx * 8];
            *(float4*)&b[4] = *(const float4*)&Bs[k][tx * 8 + 4];
            #pragma unroll
            for (int i = 0; i < 8; ++i)
                #pragma unroll
                for (int j = 0; j < 8; ++j)
                    acc[i][j] += a[i] * b[j];
        }
    }

    const int row0 = bm * 128 + ty * 8;
    const int col0 = bn * 128 + tx * 8;
    float bias[8];
    #pragma unroll
    for (int j = 0; j < 8; ++j) {
        int c = col0 + j;
        bias[j] = (c < 1024) ? b_ru[c] : b_c[c - 1024];
    }
    #pragma unroll
    for (int i = 0; i < 8; ++i) {
        float4 v0 = make_float4(acc[i][0] + bias[0], acc[i][1] + bias[1],
                                acc[i][2] + bias[2], acc[i][3] + bias[3]);
        float4 v1 = make_float4(acc[i][4] + bias[4], acc[i][5] + bias[5],
                                acc[i][6] + bias[6], acc[i][7] + bias[7]);
        float* p = pre + (size_t)(row0 + i) * NG + col0;
        *(float4*)p = v0;
        *(float4*)(p + 4) = v1;
    }
}

// ---------------- persistent cooperative recurrence ------------------------
// 256 blocks x 256 threads.  Block (g = bid&3, slice = bid>>2) holds the
// slice's Wr/Wz/Wc rows (48 KB LDS, loaded once).  Each of the block's 4
// waves is an INDEPENDENT sync domain (batch-pair bp): wave handles batches
// g*8+bp*2..+1 for its slice.  Sync = per-domain counting barriers:
// arrive = fire-and-forget release atomic_add to one 64B line; wait =
// single-line relaxed poll (R4 regression root-caused as poll-request
// congestion of L3; this is ~60x less pressure, zero extra hops).
// All cross-wave data via agent-scope (sc1) accesses; h/rh parity
// double-buffered; counters are monotonic running sums (64 adds/step).
__global__ __launch_bounds__(THREADS, 1) void gru_rec(
        const float* __restrict__ W_ru, const float* __restrict__ W_c,
        const float* __restrict__ pre, float* __restrict__ h_buf,
        float* __restrict__ rh_buf, unsigned* __restrict__ cnt,
        float* __restrict__ out, float* __restrict__ hlast,
        int t0, int Tc) {
    __shared__ float Wl[3 * JB * LDW];       // 48 KB
    float* Wr_s = Wl;
    float* Wz_s = Wl + JB * LDW;
    float* Wc_s = Wl + 2 * JB * LDW;

    const int bid    = blockIdx.x;
    const int g      = bid & 3;              // group
    const int slice  = bid >> 2;             // 0..63
    const int j0     = slice * JB;
    const int tid    = threadIdx.x;
    const int bp     = tid >> 6;             // wave id = batch-pair / domain
    const int l      = tid & 63;
    const int jj_own = l & 7;                // owner column (lanes 0..15)
    const int b_loc  = (l >> 3) & 1;         // owner batch within pair
    const int bg0    = g * 8 + bp * 2;       // first batch of this wave's pair
    const int b_own  = bg0 + b_loc;

    unsigned* cnt_h  = cnt + (size_t)((g * BPAIRS + bp) * 2 + 0) * FSTR;
    unsigned* cnt_rh = cnt + (size_t)((g * BPAIRS + bp) * 2 + 1) * FSTR;

    // one-time LDS fill: rows j0..j0+7 of Wh_r, Wh_z, Wh_c (k-contiguous)
    for (int idx = tid; idx < JB * 512; idx += THREADS) {
        int jj = idx >> 9, k = idx & 511;
        Wr_s[jj * LDW + k] = W_ru[(size_t)(j0 + jj) * 1024 + k];
        Wz_s[jj * LDW + k] = W_ru[(size_t)(512 + j0 + jj) * 1024 + k];
        Wc_s[jj * LDW + k] = W_c [(size_t)(j0 + jj) * 1024 + k];
    }
    __syncthreads();   // the ONLY barrier; waves are independent after this

    for (int t = 0; t < Tc; ++t) {
        const unsigned s = (unsigned)(t0 + t);   // global step (counters monotonic)

        // plain cached loads of the input-projection terms (owner lanes);
        // issued before the wait so the L2 miss overlaps the poll.
        const float* prow = pre + ((size_t)t * Bsz + b_own) * NG;
        float pg_r = prow[j0 + jj_own];
        float pg_z = prow[512 + j0 + jj_own];
        float pg_c = prow[1024 + j0 + jj_own];

        // ---- phase A: wait h(s), compute r,z, publish rh(s) ----
        if (s) wait_cnt(cnt_h, 64u * s);

        const float* hrow = h_buf + ((size_t)(s & 1) * Bsz + bg0) * Hsz;
        float h_own = ld_agent(hrow + (size_t)b_loc * Hsz + j0 + jj_own);
        f32x4 h00, h01, h10, h11;     // [batch][k-quadrant]
        ld4_agent(hrow + l * 4, h00, h01, h10, h11);

        float ar0[8], ar1[8], az0[8], az1[8];
        #pragma unroll
        for (int jj = 0; jj < 8; ++jj) { ar0[jj]=0.f; ar1[jj]=0.f; az0[jj]=0.f; az1[jj]=0.f; }
        {
            const int kb0 = l * 4;
            #pragma unroll
            for (int jj = 0; jj < 8; ++jj) {
                const f32x4 wr = *(const f32x4*)&Wr_s[jj * LDW + kb0];
                const f32x4 wz = *(const f32x4*)&Wz_s[jj * LDW + kb0];
                ar0[jj] += wr.x*h00.x + wr.y*h00.y + wr.z*h00.z + wr.w*h00.w;
                ar1[jj] += wr.x*h10.x + wr.y*h10.y + wr.z*h10.z + wr.w*h10.w;
                az0[jj] += wz.x*h00.x + wz.y*h00.y + wz.z*h00.z + wz.w*h00.w;
                az1[jj] += wz.x*h10.x + wz.y*h10.y + wz.z*h10.z + wz.w*h10.w;
            }
            const int kb1 = 256 + l * 4;
            #pragma unroll
            for (int jj = 0; jj < 8; ++jj) {
                const f32x4 wr = *(const f32x4*)&Wr_s[jj * LDW + kb1];
                const f32x4 wz = *(const f32x4*)&Wz_s[jj * LDW + kb1];
                ar0[jj] += wr.x*h01.x + wr.y*h01.y + wr.z*h01.z + wr.w*h01.w;
                ar1[jj] += wr.x*h11.x + wr.y*h11.y + wr.z*h11.z + wr.w*h11.w;
                az0[jj] += wz.x*h01.x + wz.y*h01.y + wz.z*h01.z + wz.w*h01.w;
                az1[jj] += wz.x*h11.x + wz.y*h11.y + wz.z*h11.z + wz.w*h11.w;
            }
        }
        float rsum = fold_b(fold8(ar0, l), fold8(ar1, l), l);
        float zsum = fold_b(fold8(az0, l), fold8(az1, l), l);

        float r = sigmoidf_(rsum + pg_r);
        float z = sigmoidf_(zsum + pg_z);
        float* rrow = rh_buf + ((size_t)(s & 1) * Bsz + b_own) * Hsz;
        if (l < 16) st_agent(rrow + j0 + jj_own, r * h_own);
        if (l == 0) arrive(cnt_rh);               // release: drains rh stores

        // ---- phase B: wait rh(s), compute cand + h(s+1), publish ----
        wait_cnt(cnt_rh, 64u * (s + 1));

        const float* rrow0 = rh_buf + ((size_t)(s & 1) * Bsz + bg0) * Hsz;
        f32x4 r00, r01, r10, r11;
        ld4_agent(rrow0 + l * 4, r00, r01, r10, r11);

        float ac0[8], ac1[8];
        #pragma unroll
        for (int jj = 0; jj < 8; ++jj) { ac0[jj]=0.f; ac1[jj]=0.f; }
        {
            const int kb0 = l * 4;
            #pragma unroll
            for (int jj = 0; jj < 8; ++jj) {
                const f32x4 wc = *(const f32x4*)&Wc_s[jj * LDW + kb0];
                ac0[jj] += wc.x*r00.x + wc.y*r00.y + wc.z*r00.z + wc.w*r00.w;
                ac1[jj] += wc.x*r10.x + wc.y*r10.y + wc.z*r10.z + wc.w*r10.w;
            }
            const int kb1 = 256 + l * 4;
            #pragma unroll
            for (int jj = 0; jj < 8; ++jj) {
                const f32x4 wc = *(const f32x4*)&Wc_s[jj * LDW + kb1];
                ac0[jj] += wc.x*r01.x + wc.y*r01.y + wc.z*r01.z + wc.w*r01.w;
                ac1[jj] += wc.x*r11.x + wc.y*r11.y + wc.z*r11.z + wc.w*r11.w;
            }
        }
        float csum = fold_b(fold8(ac0, l), fold8(ac1, l), l);

        float c  = tanhf_(csum + pg_c);
        float hn = h_own + z * (c - h_own);      // (1-z)h + z*c
        float* hw = h_buf + ((size_t)((s + 1) & 1) * Bsz + b_own) * Hsz;
        if (l < 16) st_agent(hw + j0 + jj_own, hn);
        if (l == 0) arrive(cnt_h);               // release: drains h stores
        // out/hlast stores AFTER the arrive: HBM store ack off the critical
        // path (drained by next step's release arrive).
        if (l < 16) {
            out[((size_t)b_own * Lsz + s) * Hsz + j0 + jj_own] = hn;
            if (s == Lsz - 1) hlast[(size_t)b_own * Hsz + j0 + jj_own] = hn;
        }
    }
}

// ---------------------------------------------------------------------------
extern "C" void kernel_launch(void* const* d_in, const int* in_sizes, int n_in,
                              void* d_out, int out_size, void* d_ws, size_t ws_size,
                              hipStream_t stream) {
    const float* x     = (const float*)d_in[0];
    const float* h0    = (const float*)d_in[1];
    const float* W_ru  = (const float*)d_in[2];
    const float* b_ru  = (const float*)d_in[3];
    const float* W_c   = (const float*)d_in[4];
    const float* b_c   = (const float*)d_in[5];
    float* out   = (float*)d_out;
    float* hlast = out + (size_t)Bsz * Lsz * Hsz;

    // 16 domains x {cnt_h, cnt_rh} x 64B
    const int ncnt = NDOM * 2 * FSTR;             // 512 u32

    float* ws       = (float*)d_ws;
    unsigned* cnt   = (unsigned*)ws;
    float* h_buf    = ws + ncnt;                  // 2 x 32 x 512 (parity-major)
    float* rh_buf   = h_buf + 2 * Bsz * Hsz;      // 2 x 32 x 512
    float* pre      = rh_buf + 2 * Bsz * Hsz;     // Tc*32*1536

    const size_t fixed_bytes = (size_t)(ncnt + 4 * Bsz * Hsz) * 4;
    int Tc = 256;
    while (Tc > 8 && fixed_bytes + (size_t)Tc * Bsz * NG * 4 > ws_size) Tc >>= 1;

    hipMemsetAsync(cnt, 0, ncnt * sizeof(unsigned), stream);  // once: counters are
    init_h<<<(Bsz * Hsz) / 256, 256, 0, stream>>>(h0, h_buf); // global running sums

    const int nchunks = Lsz / Tc;
    for (int cidx = 0; cidx < nchunks; ++cidx) {
        int t0 = cidx * Tc;
        gemm_pre<<<dim3((Tc * Bsz) / 128, NG / 128), 256, 0, stream>>>(
            x, W_ru, b_ru, W_c, b_c, pre, t0);
        void* args[] = {(void*)&W_ru, (void*)&W_c, (void*)&pre, (void*)&h_buf,
                        (void*)&rh_buf, (void*)&cnt, (void*)&out, (void*)&hlast,
                        (void*)&t0, (void*)&Tc};
        hipLaunchCooperativeKernel(reinterpret_cast<void*>(gru_rec),
                                   dim3(NBLK), dim3(THREADS), args, 0u, stream);
    }
}

// Round 7
// 13595.683 us; speedup vs baseline: 2.4814x; 2.4814x over previous
//
#include <hip/hip_runtime.h>
#include <cstddef>
#include <cstdint>

// Problem: GRU  B=32, L=1024, D_IN=512, H=512
// outputs: outs(32,1024,512) then h_last(32,512), flat in d_out.

#define Bsz   32
#define Lsz   1024
#define Hsz   512
#define NG    1536   // 1024 ru gates + 512 cand

// recurrence decomposition
#define NBLK    256   // blocks (co-resident, cooperative launch)
#define GROUPS  4     // batch groups (8 batches each)
#define SLICES  64    // weight slices per group (one block each)
#define BPAIRS  4     // batch-pairs per group = waves per block (independent sync domains)
#define NDOM    (GROUPS * BPAIRS)   // 16 sync domains
#define JB      8     // h-columns owned per slice
#define LDW     512   // LDS row stride in floats (16B aligned, contiguous b128 reads)
#define THREADS 256
#define FSTR    16    // counter stride in u32 (64B: one cache line per counter)

typedef float f32x4 __attribute__((ext_vector_type(4)));

__device__ __forceinline__ float sigmoidf_(float v) {
    return 1.0f / (1.0f + __expf(-v));
}
__device__ __forceinline__ float tanhf_(float v) {
    float e = __expf(2.0f * v);           // inf -> 1, 0 -> -1 : correct saturation
    return 1.0f - 2.0f / (e + 1.0f);
}
// agent-scope (device) accesses; L3 is the coherence point.  ALL cross-wave
// data uses agent scope on BOTH sides.  NO release/acquire anywhere in the
// steady state: agent-RELEASE emits buffer_wbl2 (L2-wide dirty writeback)
// and agent-ACQUIRE emits L2 invalidate -- whole-cache maintenance ops that
// profiling (R1..R6) shows cost ~10-16us per sync phase on a 512-step serial
// chain.  sc1 ops complete AT L3, so ordering via s_waitcnt vmcnt(0) +
// issue order is sufficient (fence-free message passing via completion).
__device__ __forceinline__ float ld_agent(const float* p) {
    return __hip_atomic_load(p, __ATOMIC_RELAXED, __HIP_MEMORY_SCOPE_AGENT);
}
__device__ __forceinline__ void st_agent(float* p, float v) {
    __hip_atomic_store(p, v, __ATOMIC_RELAXED, __HIP_MEMORY_SCOPE_AGENT);
}
// four agent-scope (sc1) 16B loads, one waitcnt.  The internal vmcnt(0) also
// guarantees these loads COMPLETE before any later arrive-add in this wave
// (the WAR handshake relies on this).
__device__ __forceinline__ void ld4_agent(const float* p, f32x4& a, f32x4& b,
                                          f32x4& c, f32x4& d) {
    asm volatile(
        "global_load_dwordx4 %0, %4, off sc1\n\t"
        "global_load_dwordx4 %1, %4, off offset:1024 sc1\n\t"
        "global_load_dwordx4 %2, %4, off offset:2048 sc1\n\t"
        "global_load_dwordx4 %3, %4, off offset:3072 sc1\n\t"
        "s_waitcnt vmcnt(0)"
        : "=&v"(a), "=&v"(b), "=&v"(c), "=&v"(d)
        : "v"(p)
        : "memory");
}

// ---- counting barrier primitives (single line per domain-phase) ----------
// drain: all of this wave's outstanding sc1 data stores complete at L3.
// (compiler-level memory clobber pins surrounding memory ops.)
__device__ __forceinline__ void drain_stores() {
    asm volatile("s_waitcnt vmcnt(0)" ::: "memory");
}
// arrive: fire-and-forget RELAXED RMW (no wbl2, no return value; adds from
// the 64 slices pipeline into one L3 bank).  Must be preceded by
// drain_stores() so the count only advances after data is at L3.
__device__ __forceinline__ void arrive(unsigned* c) {
    __hip_atomic_fetch_add(c, 1u, __ATOMIC_RELAXED, __HIP_MEMORY_SCOPE_AGENT);
}
// wait: all 64 lanes poll ONE address (one coalesced request per iteration)
// with sleep backoff.  RELAXED: no per-poll invalidate.  Running-sum
// threshold 64*s bounds inter-slice skew to exactly 1 step (if any slice
// exceeded min+1, total >= 64(m+1) while sum <= 64m+63) -- which is what the
// parity double-buffers require.
__device__ __forceinline__ void wait_cnt(const unsigned* c, unsigned target) {
    while (__hip_atomic_load(c, __ATOMIC_RELAXED, __HIP_MEMORY_SCOPE_AGENT) < target)
        __builtin_amdgcn_s_sleep(1);
}

// fold an 8-array over lane-xor {1,2,4}: returns this lane's partial sum of
// element (l&7) over its 8-lane subgroup.  Partition-agnostic over k.
__device__ __forceinline__ float fold8(float a[8], int l) {
    #pragma unroll
    for (int i = 0; i < 4; ++i) {
        float lo = a[2 * i], hi = a[2 * i + 1];
        float ex = __shfl_xor((l & 1) ? lo : hi, 1);
        a[i] = (l & 1) ? (hi + ex) : (lo + ex);
    }
    #pragma unroll
    for (int i = 0; i < 2; ++i) {
        float lo = a[2 * i], hi = a[2 * i + 1];
        float ex = __shfl_xor((l & 2) ? lo : hi, 2);
        a[i] = (l & 2) ? (hi + ex) : (lo + ex);
    }
    float lo = a[0], hi = a[1];
    float ex = __shfl_xor((l & 4) ? lo : hi, 4);
    return (l & 4) ? (hi + ex) : (lo + ex);
}
// combine batch0/batch1 partials over xor8 (lane keeps batch (l>>3)&1),
// then full-add over xor16/xor32.  Result: lane l holds the COMPLETE k-sum
// for (batch=(l>>3)&1, column=l&7); lanes 0..15 are the owners.
__device__ __forceinline__ float fold_b(float p0, float p1, int l) {
    float send = (l & 8) ? p0 : p1;
    float ex   = __shfl_xor(send, 8);
    float keep = (l & 8) ? p1 : p0;
    float v = keep + ex;
    v += __shfl_xor(v, 16);
    v += __shfl_xor(v, 32);
    return v;
}

__global__ __launch_bounds__(256) void init_h(const float* __restrict__ h0,
                                              float* __restrict__ hstate) {
    int i = blockIdx.x * 256 + threadIdx.x;
    hstate[i] = h0[i];   // parity-0 buffer
}

// ---------------- input-projection GEMM (unchanged) ------------------------
__global__ __launch_bounds__(256) void gemm_pre(const float* __restrict__ x,
                                                const float* __restrict__ W_ru,
                                                const float* __restrict__ b_ru,
                                                const float* __restrict__ W_c,
                                                const float* __restrict__ b_c,
                                                float* __restrict__ pre,
                                                int t0) {
    __shared__ float As[8][128];
    __shared__ float Bs[8][128];
    const int tid = threadIdx.x;
    const int bm = blockIdx.x, bn = blockIdx.y;
    const int tx = tid & 15, ty = tid >> 4;

    const int lrow = tid >> 1;
    const int lk4  = (tid & 1) * 4;
    const int grow = bm * 128 + lrow;          // row = t_local*32 + b
    const int tt = grow >> 5, bb = grow & 31;
    const float* xrow = x + ((size_t)bb * Lsz + (t0 + tt)) * 512;
    const int gn = bn * 128 + lrow;            // output column (gate index)
    const float* wrow = (gn < 1024) ? (W_ru + (size_t)gn * 1024 + 512)
                                    : (W_c  + (size_t)(gn - 1024) * 1024 + 512);

    float acc[8][8];
    #pragma unroll
    for (int i = 0; i < 8; ++i)
        #pragma unroll
        for (int j = 0; j < 8; ++j) acc[i][j] = 0.0f;

    for (int k0 = 0; k0 < 512; k0 += 8) {
        float4 av = *(const float4*)(xrow + k0 + lk4);
        float4 bv = *(const float4*)(wrow + k0 + lk4);
        __syncthreads();
        As[lk4 + 0][lrow] = av.x; As[lk4 + 1][lrow] = av.y;
        As[lk4 + 2][lrow] = av.z; As[lk4 + 3][lrow] = av.w;
        Bs[lk4 + 0][lrow] = bv.x; Bs[lk4 + 1][lrow] = bv.y;
        Bs[lk4 + 2][lrow] = bv.z; Bs[lk4 + 3][lrow] = bv.w;
        __syncthreads();
        #pragma unroll
        for (int k = 0; k < 8; ++k) {
            float a[8], b[8];
            *(float4*)&a[0] = *(const float4*)&As[k][ty * 8];
            *(float4*)&a[4] = *(const float4*)&As[k][ty * 8 + 4];
            *(float4*)&b[0] = *(const float4*)&Bs[k][tx * 8];
            *(float4*)&b[4] = *(const float4*)&Bs[k][tx * 8 + 4];
            #pragma unroll
            for (int i = 0; i < 8; ++i)
                #pragma unroll
                for (int j = 0; j < 8; ++j)
                    acc[i][j] += a[i] * b[j];
        }
    }

    const int row0 = bm * 128 + ty * 8;
    const int col0 = bn * 128 + tx * 8;
    float bias[8];
    #pragma unroll
    for (int j = 0; j < 8; ++j) {
        int c = col0 + j;
        bias[j] = (c < 1024) ? b_ru[c] : b_c[c - 1024];
    }
    #pragma unroll
    for (int i = 0; i < 8; ++i) {
        float4 v0 = make_float4(acc[i][0] + bias[0], acc[i][1] + bias[1],
                                acc[i][2] + bias[2], acc[i][3] + bias[3]);
        float4 v1 = make_float4(acc[i][4] + bias[4], acc[i][5] + bias[5],
                                acc[i][6] + bias[6], acc[i][7] + bias[7]);
        float* p = pre + (size_t)(row0 + i) * NG + col0;
        *(float4*)p = v0;
        *(float4*)(p + 4) = v1;
    }
}

// ---------------- persistent cooperative recurrence ------------------------
// 256 blocks x 256 threads.  Block (g = bid&3, slice = bid>>2) holds the
// slice's Wr/Wz/Wc rows (48 KB LDS, loaded once).  Each of the block's 4
// waves is an INDEPENDENT sync domain (batch-pair bp): wave handles batches
// g*8+bp*2..+1 for its slice.  Sync = per-domain counting barriers with
// FENCE-FREE message passing: sc1 data stores -> vmcnt(0) drain -> relaxed
// fetch_add; consumer polls one line relaxed, then issues sc1 data loads.
// No buffer_wbl2 / invalidate anywhere in the loop (R1-R6 post-mortem:
// compiler-emitted cache maintenance around release/acquire was the
// dominant per-phase cost).  h/rh parity double-buffered; counters are
// monotonic running sums (64 adds/step).
__global__ __launch_bounds__(THREADS, 1) void gru_rec(
        const float* __restrict__ W_ru, const float* __restrict__ W_c,
        const float* __restrict__ pre, float* __restrict__ h_buf,
        float* __restrict__ rh_buf, unsigned* __restrict__ cnt,
        float* __restrict__ out, float* __restrict__ hlast,
        int t0, int Tc) {
    __shared__ float Wl[3 * JB * LDW];       // 48 KB
    float* Wr_s = Wl;
    float* Wz_s = Wl + JB * LDW;
    float* Wc_s = Wl + 2 * JB * LDW;

    const int bid    = blockIdx.x;
    const int g      = bid & 3;              // group
    const int slice  = bid >> 2;             // 0..63
    const int j0     = slice * JB;
    const int tid    = threadIdx.x;
    const int bp     = tid >> 6;             // wave id = batch-pair / domain
    const int l      = tid & 63;
    const int jj_own = l & 7;                // owner column (lanes 0..15)
    const int b_loc  = (l >> 3) & 1;         // owner batch within pair
    const int bg0    = g * 8 + bp * 2;       // first batch of this wave's pair
    const int b_own  = bg0 + b_loc;

    unsigned* cnt_h  = cnt + (size_t)((g * BPAIRS + bp) * 2 + 0) * FSTR;
    unsigned* cnt_rh = cnt + (size_t)((g * BPAIRS + bp) * 2 + 1) * FSTR;

    // one-time LDS fill: rows j0..j0+7 of Wh_r, Wh_z, Wh_c (k-contiguous)
    for (int idx = tid; idx < JB * 512; idx += THREADS) {
        int jj = idx >> 9, k = idx & 511;
        Wr_s[jj * LDW + k] = W_ru[(size_t)(j0 + jj) * 1024 + k];
        Wz_s[jj * LDW + k] = W_ru[(size_t)(512 + j0 + jj) * 1024 + k];
        Wc_s[jj * LDW + k] = W_c [(size_t)(j0 + jj) * 1024 + k];
    }
    __syncthreads();   // the ONLY barrier; waves are independent after this

    for (int t = 0; t < Tc; ++t) {
        const unsigned s = (unsigned)(t0 + t);   // global step (counters monotonic)

        // plain cached loads of the input-projection terms (owner lanes);
        // issued before the wait so the L2 miss overlaps the poll.
        const float* prow = pre + ((size_t)t * Bsz + b_own) * NG;
        float pg_r = prow[j0 + jj_own];
        float pg_z = prow[512 + j0 + jj_own];
        float pg_c = prow[1024 + j0 + jj_own];

        // ---- phase A: wait h(s), compute r,z, publish rh(s) ----
        if (s) wait_cnt(cnt_h, 64u * s);

        const float* hrow = h_buf + ((size_t)(s & 1) * Bsz + bg0) * Hsz;
        float h_own = ld_agent(hrow + (size_t)b_loc * Hsz + j0 + jj_own);
        f32x4 h00, h01, h10, h11;     // [batch][k-quadrant]
        ld4_agent(hrow + l * 4, h00, h01, h10, h11);

        float ar0[8], ar1[8], az0[8], az1[8];
        #pragma unroll
        for (int jj = 0; jj < 8; ++jj) { ar0[jj]=0.f; ar1[jj]=0.f; az0[jj]=0.f; az1[jj]=0.f; }
        {
            const int kb0 = l * 4;
            #pragma unroll
            for (int jj = 0; jj < 8; ++jj) {
                const f32x4 wr = *(const f32x4*)&Wr_s[jj * LDW + kb0];
                const f32x4 wz = *(const f32x4*)&Wz_s[jj * LDW + kb0];
                ar0[jj] += wr.x*h00.x + wr.y*h00.y + wr.z*h00.z + wr.w*h00.w;
                ar1[jj] += wr.x*h10.x + wr.y*h10.y + wr.z*h10.z + wr.w*h10.w;
                az0[jj] += wz.x*h00.x + wz.y*h00.y + wz.z*h00.z + wz.w*h00.w;
                az1[jj] += wz.x*h10.x + wz.y*h10.y + wz.z*h10.z + wz.w*h10.w;
            }
            const int kb1 = 256 + l * 4;
            #pragma unroll
            for (int jj = 0; jj < 8; ++jj) {
                const f32x4 wr = *(const f32x4*)&Wr_s[jj * LDW + kb1];
                const f32x4 wz = *(const f32x4*)&Wz_s[jj * LDW + kb1];
                ar0[jj] += wr.x*h01.x + wr.y*h01.y + wr.z*h01.z + wr.w*h01.w;
                ar1[jj] += wr.x*h11.x + wr.y*h11.y + wr.z*h11.z + wr.w*h11.w;
                az0[jj] += wz.x*h01.x + wz.y*h01.y + wz.z*h01.z + wz.w*h01.w;
                az1[jj] += wz.x*h11.x + wz.y*h11.y + wz.z*h11.z + wz.w*h11.w;
            }
        }
        float rsum = fold_b(fold8(ar0, l), fold8(ar1, l), l);
        float zsum = fold_b(fold8(az0, l), fold8(az1, l), l);

        float r = sigmoidf_(rsum + pg_r);
        float z = sigmoidf_(zsum + pg_z);
        float* rrow = rh_buf + ((size_t)(s & 1) * Bsz + b_own) * Hsz;
        if (l < 16) st_agent(rrow + j0 + jj_own, r * h_own);
        drain_stores();                           // rh at L3 before count advances
        if (l == 0) arrive(cnt_rh);

        // ---- phase B: wait rh(s), compute cand + h(s+1), publish ----
        wait_cnt(cnt_rh, 64u * (s + 1));

        const float* rrow0 = rh_buf + ((size_t)(s & 1) * Bsz + bg0) * Hsz;
        f32x4 r00, r01, r10, r11;
        ld4_agent(rrow0 + l * 4, r00, r01, r10, r11);

        float ac0[8], ac1[8];
        #pragma unroll
        for (int jj = 0; jj < 8; ++jj) { ac0[jj]=0.f; ac1[jj]=0.f; }
        {
            const int kb0 = l * 4;
            #pragma unroll
            for (int jj = 0; jj < 8; ++jj) {
                const f32x4 wc = *(const f32x4*)&Wc_s[jj * LDW + kb0];
                ac0[jj] += wc.x*r00.x + wc.y*r00.y + wc.z*r00.z + wc.w*r00.w;
                ac1[jj] += wc.x*r10.x + wc.y*r10.y + wc.z*r10.z + wc.w*r10.w;
            }
            const int kb1 = 256 + l * 4;
            #pragma unroll
            for (int jj = 0; jj < 8; ++jj) {
                const f32x4 wc = *(const f32x4*)&Wc_s[jj * LDW + kb1];
                ac0[jj] += wc.x*r01.x + wc.y*r01.y + wc.z*r01.z + wc.w*r01.w;
                ac1[jj] += wc.x*r11.x + wc.y*r11.y + wc.z*r11.z + wc.w*r11.w;
            }
        }
        float csum = fold_b(fold8(ac0, l), fold8(ac1, l), l);

        float c  = tanhf_(csum + pg_c);
        float hn = h_own + z * (c - h_own);      // (1-z)h + z*c
        float* hw = h_buf + ((size_t)((s + 1) & 1) * Bsz + b_own) * Hsz;
        if (l < 16) st_agent(hw + j0 + jj_own, hn);
        drain_stores();                           // h at L3 before count advances
        if (l == 0) arrive(cnt_h);
        // out/hlast stores AFTER the arrive: HBM store ack off the critical
        // path (their completion is only awaited by the NEXT drain).
        if (l < 16) {
            out[((size_t)b_own * Lsz + s) * Hsz + j0 + jj_own] = hn;
            if (s == Lsz - 1) hlast[(size_t)b_own * Hsz + j0 + jj_own] = hn;
        }
    }
}

// ---------------------------------------------------------------------------
extern "C" void kernel_launch(void* const* d_in, const int* in_sizes, int n_in,
                              void* d_out, int out_size, void* d_ws, size_t ws_size,
                              hipStream_t stream) {
    const float* x     = (const float*)d_in[0];
    const float* h0    = (const float*)d_in[1];
    const float* W_ru  = (const float*)d_in[2];
    const float* b_ru  = (const float*)d_in[3];
    const float* W_c   = (const float*)d_in[4];
    const float* b_c   = (const float*)d_in[5];
    float* out   = (float*)d_out;
    float* hlast = out + (size_t)Bsz * Lsz * Hsz;

    // 16 domains x {cnt_h, cnt_rh} x 64B
    const int ncnt = NDOM * 2 * FSTR;             // 512 u32

    float* ws       = (float*)d_ws;
    unsigned* cnt   = (unsigned*)ws;
    float* h_buf    = ws + ncnt;                  // 2 x 32 x 512 (parity-major)
    float* rh_buf   = h_buf + 2 * Bsz * Hsz;      // 2 x 32 x 512
    float* pre      = rh_buf + 2 * Bsz * Hsz;     // Tc*32*1536

    const size_t fixed_bytes = (size_t)(ncnt + 4 * Bsz * Hsz) * 4;
    int Tc = 256;
    while (Tc > 8 && fixed_bytes + (size_t)Tc * Bsz * NG * 4 > ws_size) Tc >>= 1;

    hipMemsetAsync(cnt, 0, ncnt * sizeof(unsigned), stream);  // once: counters are
    init_h<<<(Bsz * Hsz) / 256, 256, 0, stream>>>(h0, h_buf); // global running sums

    const int nchunks = Lsz / Tc;
    for (int cidx = 0; cidx < nchunks; ++cidx) {
        int t0 = cidx * Tc;
        gemm_pre<<<dim3((Tc * Bsz) / 128, NG / 128), 256, 0, stream>>>(
            x, W_ru, b_ru, W_c, b_c, pre, t0);
        void* args[] = {(void*)&W_ru, (void*)&W_c, (void*)&pre, (void*)&h_buf,
                        (void*)&rh_buf, (void*)&cnt, (void*)&out, (void*)&hlast,
                        (void*)&t0, (void*)&Tc};
        hipLaunchCooperativeKernel(reinterpret_cast<void*>(gru_rec),
                                   dim3(NBLK), dim3(THREADS), args, 0u, stream);
    }
}